// Round 4
// baseline (258.002 us; speedup 1.0000x reference)
//
#include <hip/hip_runtime.h>

#define BB 8
#define CC_ALL 128
#define HH 96
#define WW 128
#define PP 9
#define RAD 4
#define YT 2            // y rows per block
#define CCH 8           // channels per chunk
#define NCHUNK (CC_ALL / CCH)   // 16
#define PX 8            // x pixels per thread
#define NXG (WW / PX)   // 16 x-groups
#define ROWS2 (YT + PP - 1)     // 10 in2 rows staged
#define GS 137                  // granule stride per row (136 + 1 pad)
#define NG2 (ROWS2 * (WW + 8))  // 1360 in2 granules per chunk
#define NG1 (YT * WW)           // 256 in1 granules per chunk
#define NTHREADS 288            // 2 rows * 9 di * 16 xg

// clang's amdgcn builtins use __fp16 vectors ('h' encoding), not _Float16.
typedef __fp16 h2 __attribute__((ext_vector_type(2)));
union HU { unsigned int u; h2 h; };

__device__ __forceinline__ unsigned int pk(float a, float b) {
    HU r; r.h = __builtin_amdgcn_cvt_pkrtz(a, b); return r.u;
}

__device__ __forceinline__ float dot2(unsigned int a, unsigned int b, float c) {
#if __has_builtin(__builtin_amdgcn_fdot2)
    HU ua, ub; ua.u = a; ub.u = b;
    return __builtin_amdgcn_fdot2(ua.h, ub.h, c, false);
#else
    float r;
    asm volatile("v_dot2_f32_f16 %0, %1, %2, %3" : "=v"(r) : "v"(a), "v"(b), "v"(c));
    return r;
#endif
}

// XOR swizzle at 16B-granule level: spreads stride-8-granule accesses across
// bank groups (bank-group = granule & 7). Bijective within each 8-granule run.
__device__ __forceinline__ int swz(int g) { return g ^ ((g >> 3) & 7); }

__global__ __launch_bounds__(NTHREADS, 4)
void corr_kernel(const float* __restrict__ in1, const float* __restrict__ in2,
                 float* __restrict__ out)
{
    __shared__ uint4 s2g[ROWS2 * GS];   // in2: [row][swz(lx)] -> 8 f16 channels
    __shared__ uint4 s1g[YT * GS];      // in1: [row][swz(x)]  -> 8 f16 channels

    const int tid = threadIdx.x;
    const int y0  = blockIdx.x * YT;
    const int b   = blockIdx.y;

    // compute-phase role: (yl, di, xg), xg fastest (16-lane groups share di)
    const int yl  = tid / (PP * NXG);          // 0..1
    const int rem = tid - yl * (PP * NXG);
    const int di  = rem >> 4;                  // 0..8
    const int xg  = rem & 15;                  // 0..15
    const int x0  = xg * PX;

    float acc[PP][PX];
    #pragma unroll
    for (int j = 0; j < PP; ++j)
        #pragma unroll
        for (int p = 0; p < PX; ++p) acc[j][p] = 0.f;

    const int chs = HH * WW;                   // 12288, channel stride
    const float* b1 = in1 + (size_t)b * CC_ALL * chs;
    const float* b2 = in2 + (size_t)b * CC_ALL * chs;

    for (int cc = 0; cc < NCHUNK; ++cc) {
        const int c0 = cc * CCH;

        // ---------------- stage (channel-transpose into f16 granules) -------
        #pragma unroll
        for (int k = 0; k < 6; ++k) {
            int s = tid + k * NTHREADS;
            if (s < NG2) {
                int row = s / (WW + 8);
                int lx  = s - row * (WW + 8);
                int gy  = y0 - RAD + row;
                int gx  = lx - RAD;
                bool valid = ((unsigned)gy < HH) && ((unsigned)gx < WW);
                const float* src = b2 + c0 * chs + gy * WW + gx;
                float f[CCH];
                #pragma unroll
                for (int j = 0; j < CCH; ++j)
                    f[j] = valid ? src[j * chs] : 0.f;
                uint4 g;
                g.x = pk(f[0], f[1]); g.y = pk(f[2], f[3]);
                g.z = pk(f[4], f[5]); g.w = pk(f[6], f[7]);
                s2g[row * GS + swz(lx)] = g;
            } else if (s < NG2 + NG1) {
                int t   = s - NG2;
                int row = t >> 7;              // /128
                int x   = t & (WW - 1);
                const float* src = b1 + c0 * chs + (y0 + row) * WW + x;
                float f[CCH];
                #pragma unroll
                for (int j = 0; j < CCH; ++j) f[j] = src[j * chs];
                uint4 g;
                g.x = pk(f[0], f[1]); g.y = pk(f[2], f[3]);
                g.z = pk(f[4], f[5]); g.w = pk(f[6], f[7]);
                s1g[row * GS + swz(x)] = g;
            }
        }
        __syncthreads();

        // ---------------- compute ------------------------------------------
        uint4 a[PX];
        #pragma unroll
        for (int p = 0; p < PX; ++p)
            a[p] = s1g[yl * GS + swz(x0 + p)];

        const uint4* r2 = &s2g[(yl + di) * GS];
        #pragma unroll
        for (int w = 0; w < PX + PP - 1; ++w) {    // 16-granule window
            uint4 v = r2[swz(x0 + w)];
            #pragma unroll
            for (int dj = 0; dj < PP; ++dj) {
                int p = w - dj;                    // compile-time per (w,dj)
                if (p >= 0 && p < PX) {
                    float t = acc[dj][p];
                    t = dot2(v.x, a[p].x, t);
                    t = dot2(v.y, a[p].y, t);
                    t = dot2(v.z, a[p].z, t);
                    t = dot2(v.w, a[p].w, t);
                    acc[dj][p] = t;
                }
            }
        }
        __syncthreads();
    }

    // ---------------- epilogue: coalesced float4 stores ---------------------
    const int y = y0 + yl;
    #pragma unroll
    for (int dj = 0; dj < PP; ++dj) {
        float* op = out + ((((size_t)b * PP + di) * PP + dj) * HH + y) * WW + x0;
        float4 v0 = make_float4(acc[dj][0], acc[dj][1], acc[dj][2], acc[dj][3]);
        float4 v1 = make_float4(acc[dj][4], acc[dj][5], acc[dj][6], acc[dj][7]);
        reinterpret_cast<float4*>(op)[0] = v0;
        reinterpret_cast<float4*>(op)[1] = v1;
    }
}

extern "C" void kernel_launch(void* const* d_in, const int* in_sizes, int n_in,
                              void* d_out, int out_size, void* d_ws, size_t ws_size,
                              hipStream_t stream) {
    const float* in1 = (const float*)d_in[0];
    const float* in2 = (const float*)d_in[1];
    float* out = (float*)d_out;
    dim3 grid(HH / YT, BB);   // (48, 8)
    dim3 block(NTHREADS);
    corr_kernel<<<grid, block, 0, stream>>>(in1, in2, out);
}